// Round 2
// baseline (27.371 us; speedup 1.0000x reference)
//
#include <hip/hip_runtime.h>
#include <math.h>

#define NUM_FIELDS 24
#define VOCAB 100000
#define EMBED_DIM 64
#define BATCH 16384

// One 64-lane wave per batch element; lane index = embedding dim d.
// Each of the 24 gathers is a coalesced 256B row read (64 lanes x 4B).
__global__ __launch_bounds__(256) void fm_fwd_kernel(
    const int* __restrict__ x,          // [BATCH, NUM_FIELDS]
    const float* __restrict__ W_embed,  // [NUM_FIELDS, VOCAB, EMBED_DIM]
    const float* __restrict__ W_lin,    // [NUM_FIELDS, VOCAB]
    const float* __restrict__ bias,     // [1]
    float* __restrict__ out)            // [BATCH, 1]
{
    const int wave = (int)((blockIdx.x * blockDim.x + threadIdx.x) >> 6);
    const int lane = (int)(threadIdx.x & 63);
    if (wave >= BATCH) return;

    // Load the 24 indices for this batch element (wave-uniform broadcast loads).
    const int* xb = x + (size_t)wave * NUM_FIELDS;
    int idx[NUM_FIELDS];
#pragma unroll
    for (int i = 0; i < NUM_FIELDS / 4; ++i) {
        int4 v = reinterpret_cast<const int4*>(xb)[i];
        idx[4 * i + 0] = v.x;
        idx[4 * i + 1] = v.y;
        idx[4 * i + 2] = v.z;
        idx[4 * i + 3] = v.w;
    }

    // 24 independent gathers, fully unrolled -> all loads in flight at once.
    float sum_d = 0.f;   // sum over fields of e[f][lane]
    float ssq   = 0.f;   // sum over fields of e[f][lane]^2
#pragma unroll
    for (int f = 0; f < NUM_FIELDS; ++f) {
        float e = W_embed[((size_t)f * VOCAB + (size_t)idx[f]) * EMBED_DIM + lane];
        sum_d += e;
        ssq   += e * e;
    }

    // fm contribution per lane: 0.5*(sum_d^2 - ssq); wave-sum gives
    // 0.5*(||sum_embed||^2 - sum e^2). Fold first_order into lanes 0..23.
    float v = 0.5f * (sum_d * sum_d - ssq);
    if (lane < NUM_FIELDS) {
        v += W_lin[(size_t)lane * VOCAB + (size_t)idx[lane]];
    }

    // 64-lane butterfly reduction.
#pragma unroll
    for (int off = 32; off >= 1; off >>= 1) {
        v += __shfl_xor(v, off, 64);
    }

    if (lane == 0) {
        float logit = v + bias[0];
        out[wave] = 1.0f / (1.0f + expf(-logit));
    }
}

extern "C" void kernel_launch(void* const* d_in, const int* in_sizes, int n_in,
                              void* d_out, int out_size, void* d_ws, size_t ws_size,
                              hipStream_t stream) {
    const int*   x       = (const int*)d_in[0];
    const float* W_embed = (const float*)d_in[1];
    const float* W_lin   = (const float*)d_in[2];
    const float* bias    = (const float*)d_in[3];
    float*       out     = (float*)d_out;

    const int waves_per_block = 256 / 64;
    const int blocks = (BATCH + waves_per_block - 1) / waves_per_block;  // 4096
    fm_fwd_kernel<<<blocks, 256, 0, stream>>>(x, W_embed, W_lin, bias, out);
}